// Round 3
// baseline (888.228 us; speedup 1.0000x reference)
//
#include <hip/hip_runtime.h>

#define B_ 4096
#define T_ 128
#define F_ 64
#define H_ 32
#define G_ 128  // 4*H

__device__ __forceinline__ float sigmoid_f(float z) {
    return __builtin_amdgcn_rcpf(1.0f + __expf(-z));
}

// One wave per batch element. Gate-pair layout (cuts exchange to 2 shuffles):
//   lanes 0..31  (j=lane):    colA = j     (i_j),  colB = 32+j  (f_j)
//   lanes 32..63 (j=lane-32): colA = 64+j  (g_j),  colB = 96+j  (o_j)
// c_j lives in lo lanes; h_j computed in hi lanes; h broadcast via per-wave LDS
// (same-wave DS ops are in-order; no barrier needed).
//
// amdgpu_waves_per_eu(2,2): per-SIMD reg pool is 512 (R1/R2 evidence: waves/SIMD
// = 8/4/2/1 at 64/128/256/512). True demand ~225 arch VGPRs (192 weight regs +
// accums/temps). Without the pin, the allocator targets its own occupancy and
// AGPR-spills the weights (R2: VGPR=140 + ~190 AGPR -> 1 wave/SIMD, +45k
// accvgpr-move instrs, 563us). Pin to 2 waves/EU = 256-reg budget: fits.
extern "C" __global__
__attribute__((amdgpu_waves_per_eu(2, 2)))
__launch_bounds__(256)
void lstm_ae(const float* __restrict__ x,
             const float* __restrict__ We,
             const float* __restrict__ Ue,
             const float* __restrict__ be,
             const float* __restrict__ Wd,
             const float* __restrict__ Ud,
             const float* __restrict__ bd,
             const float* __restrict__ Wout,
             const float* __restrict__ bout,
             float* __restrict__ out)
{
    const int lane = threadIdx.x & 63;
    const int w    = threadIdx.x >> 6;
    const int b    = (blockIdx.x << 2) + w;
    const int j    = lane & 31;
    const bool lo  = lane < 32;
    const int colA = (lane & 31) | ((lane & 32) << 1);  // lo: j, hi: 64+j
    const int colB = colA + 32;                          // lo: 32+j, hi: 96+j

    __shared__ float4 xbuf4[4][2][16];  // per-wave double-buffered x row (64 floats)
    __shared__ float4 hbuf4[4][8];      // per-wave h (32 floats)
    float* hbuff = (float*)&hbuf4[w][0];

    // ---- encoder weights: register-stationary columns ----
    float weA[64], weB[64], uA[32], uB[32];
#pragma unroll
    for (int k = 0; k < 64; ++k) {
        weA[k] = We[k * G_ + colA];
        weB[k] = We[k * G_ + colB];
    }
#pragma unroll
    for (int k = 0; k < 32; ++k) {
        uA[k] = Ue[k * G_ + colA];
        uB[k] = Ue[k * G_ + colB];
    }
    const float beA = be[colA], beB = be[colB];

    const float* xrow = x + (size_t)b * (T_ * F_);

    // stage x[0]; init h in LDS
    ((float*)&xbuf4[w][0][0])[lane] = xrow[lane];
    if (lo) hbuff[lane] = 0.0f;

    float c = 0.0f;

    // =========================== encoder scan ===========================
#pragma unroll 1
    for (int t = 0; t < T_; ++t) {
        // prefetch next x row (clamped addr avoids exec-mask juggling)
        const int tn = (t + 1 < T_) ? (t + 1) : (T_ - 1);
        float xnext = xrow[tn * F_ + lane];

        // z = be + x@We + h@Ue  (per-lane: 2 gate columns)
        float zA0 = 0.f, zA1 = 0.f, zB0 = 0.f, zB1 = 0.f;
        const float4* xb = &xbuf4[w][t & 1][0];
#pragma unroll
        for (int q = 0; q < 16; ++q) {
            float4 xq = xb[q];
            int k = 4 * q;
            zA0 = fmaf(xq.x, weA[k + 0], zA0);
            zA1 = fmaf(xq.y, weA[k + 1], zA1);
            zA0 = fmaf(xq.z, weA[k + 2], zA0);
            zA1 = fmaf(xq.w, weA[k + 3], zA1);
            zB0 = fmaf(xq.x, weB[k + 0], zB0);
            zB1 = fmaf(xq.y, weB[k + 1], zB1);
            zB0 = fmaf(xq.z, weB[k + 2], zB0);
            zB1 = fmaf(xq.w, weB[k + 3], zB1);
        }
        float hA0 = 0.f, hA1 = 0.f, hB0 = 0.f, hB1 = 0.f;
#pragma unroll
        for (int q = 0; q < 8; ++q) {
            float4 hq = hbuf4[w][q];
            int k = 4 * q;
            hA0 = fmaf(hq.x, uA[k + 0], hA0);
            hA1 = fmaf(hq.y, uA[k + 1], hA1);
            hA0 = fmaf(hq.z, uA[k + 2], hA0);
            hA1 = fmaf(hq.w, uA[k + 3], hA1);
            hB0 = fmaf(hq.x, uB[k + 0], hB0);
            hB1 = fmaf(hq.y, uB[k + 1], hB1);
            hB0 = fmaf(hq.z, uB[k + 2], hB0);
            hB1 = fmaf(hq.w, uB[k + 3], hB1);
        }
        float zA = beA + (zA0 + zA1) + (hA0 + hA1);
        float zB = beB + (zB0 + zB1) + (hB0 + hB1);

        // activations: lo zA=i(sig), zB=f(sig); hi zA=g(relu), zB=o(sig)
        float sA = sigmoid_f(zA);
        float aA = lo ? sA : fmaxf(zA, 0.f);
        float aB = sigmoid_f(zB);
        float gg = __shfl_xor(aA, 32, 64);   // lo lanes receive g_j
        c = fmaf(aB, c, aA * gg);            // lo: c = f*c + i*g (hi: garbage)
        float r  = fmaxf(c, 0.f);
        float rr = __shfl_xor(r, 32, 64);    // hi lanes receive relu(c_j)
        float hv = aB * rr;                  // hi: h_j = o * relu(c)
        if (!lo) hbuff[j] = hv;              // publish h_t

        ((float*)&xbuf4[w][(t + 1) & 1][0])[lane] = xnext;   // stage x_{t+1}
    }

    // ============ decoder constant input: zd = hT@Wd + bd (once) ============
    float zdA = bd[colA], zdB = bd[colB];
#pragma unroll
    for (int q = 0; q < 8; ++q) {
        float4 hq = hbuf4[w][q];
        int k = 4 * q;
        zdA = fmaf(hq.x, Wd[(k + 0) * G_ + colA], zdA);
        zdA = fmaf(hq.y, Wd[(k + 1) * G_ + colA], zdA);
        zdA = fmaf(hq.z, Wd[(k + 2) * G_ + colA], zdA);
        zdA = fmaf(hq.w, Wd[(k + 3) * G_ + colA], zdA);
        zdB = fmaf(hq.x, Wd[(k + 0) * G_ + colB], zdB);
        zdB = fmaf(hq.y, Wd[(k + 1) * G_ + colB], zdB);
        zdB = fmaf(hq.z, Wd[(k + 2) * G_ + colB], zdB);
        zdB = fmaf(hq.w, Wd[(k + 3) * G_ + colB], zdB);
    }

    // decoder weights (encoder arrays dead -> RA reuses their registers)
    float udA[32], udB[32], wo[32];
#pragma unroll
    for (int k = 0; k < 32; ++k) {
        udA[k] = Ud[k * G_ + colA];
        udB[k] = Ud[k * G_ + colB];
        wo[k]  = Wout[k * F_ + lane];
    }
    const float bo = bout[lane];

    c = 0.f;
    if (lo) hbuff[lane] = 0.0f;   // h_{-1} = 0

    float* orow = out + (size_t)b * (T_ * F_);

    // ======= decoder scan; out-proj fused into h-read pass (1-step deferred) =======
#pragma unroll 1
    for (int t = 0; t < T_; ++t) {
        float hA0 = 0.f, hA1 = 0.f, hB0 = 0.f, hB1 = 0.f;
        float o0 = bo, o1 = 0.f;
#pragma unroll
        for (int q = 0; q < 8; ++q) {
            float4 hq = hbuf4[w][q];   // h_{t-1}
            int k = 4 * q;
            hA0 = fmaf(hq.x, udA[k + 0], hA0);
            hA1 = fmaf(hq.y, udA[k + 1], hA1);
            hA0 = fmaf(hq.z, udA[k + 2], hA0);
            hA1 = fmaf(hq.w, udA[k + 3], hA1);
            hB0 = fmaf(hq.x, udB[k + 0], hB0);
            hB1 = fmaf(hq.y, udB[k + 1], hB1);
            hB0 = fmaf(hq.z, udB[k + 2], hB0);
            hB1 = fmaf(hq.w, udB[k + 3], hB1);
            o0  = fmaf(hq.x, wo[k + 0], o0);
            o1  = fmaf(hq.y, wo[k + 1], o1);
            o0  = fmaf(hq.z, wo[k + 2], o0);
            o1  = fmaf(hq.w, wo[k + 3], o1);
        }
        if (t > 0) orow[(t - 1) * F_ + lane] = o0 + o1;  // out row for h_{t-1}

        float zA = zdA + hA0 + hA1;
        float zB = zdB + hB0 + hB1;

        float sA = sigmoid_f(zA);
        float aA = lo ? sA : fmaxf(zA, 0.f);
        float aB = sigmoid_f(zB);
        float gg = __shfl_xor(aA, 32, 64);
        c = fmaf(aB, c, aA * gg);
        float r  = fmaxf(c, 0.f);
        float rr = __shfl_xor(r, 32, 64);
        float hv = aB * rr;
        if (!lo) hbuff[j] = hv;              // publish h_t
    }

    // epilogue: out row 127 from final h
    {
        float o0 = bo, o1 = 0.f;
#pragma unroll
        for (int q = 0; q < 8; ++q) {
            float4 hq = hbuf4[w][q];
            int k = 4 * q;
            o0 = fmaf(hq.x, wo[k + 0], o0);
            o1 = fmaf(hq.y, wo[k + 1], o1);
            o0 = fmaf(hq.z, wo[k + 2], o0);
            o1 = fmaf(hq.w, wo[k + 3], o1);
        }
        orow[(T_ - 1) * F_ + lane] = o0 + o1;
    }
}

extern "C" void kernel_launch(void* const* d_in, const int* in_sizes, int n_in,
                              void* d_out, int out_size, void* d_ws, size_t ws_size,
                              hipStream_t stream) {
    (void)in_sizes; (void)n_in; (void)d_ws; (void)ws_size; (void)out_size;
    const float* x    = (const float*)d_in[0];
    const float* We   = (const float*)d_in[1];
    const float* Ue   = (const float*)d_in[2];
    const float* be   = (const float*)d_in[3];
    const float* Wd   = (const float*)d_in[4];
    const float* Ud   = (const float*)d_in[5];
    const float* bd   = (const float*)d_in[6];
    const float* Wout = (const float*)d_in[7];
    const float* bout = (const float*)d_in[8];
    float* out = (float*)d_out;

    dim3 grid(B_ / 4), block(256);
    hipLaunchKernelGGL(lstm_ae, grid, block, 0, stream,
                       x, We, Ue, be, Wd, Ud, bd, Wout, bout, out);
}

// Round 4
// 611.716 us; speedup vs baseline: 1.4520x; 1.4520x over previous
//
#include <hip/hip_runtime.h>

typedef _Float16 h2 __attribute__((ext_vector_type(2)));

#define B_ 4096
#define T_ 128
#define F_ 64
#define H_ 32
#define G_ 128  // 4*H

__device__ __forceinline__ float sigmoid_f(float z) {
    return __builtin_amdgcn_rcpf(1.0f + __expf(-z));
}

// v_dot2_f32_f16: 2 f16 MACs, fp32 accumulate, full VALU rate.
__device__ __forceinline__ float dot2(h2 a, h2 b, float c) {
#if __has_builtin(__builtin_amdgcn_fdot2)
    return __builtin_amdgcn_fdot2(a, b, c, false);
#else
    return c + (float)a.x * (float)b.x + (float)a.y * (float)b.y;
#endif
}

// One wave per batch element. Gate-pair layout:
//   lanes 0..31  (j=lane):    colA = j     (i_j),  colB = 32+j  (f_j)
//   lanes 32..63 (j=lane-32): colA = 64+j  (g_j),  colB = 96+j  (o_j)
// R1-R3 lesson: structural weight demand in fp32 is 192 regs/lane and the
// allocator hard-caps this kernel at ~128 arch VGPRs (spilling the rest to
// AGPR/scratch at 2x instr bloat). Fix: encoder path in f16-dot2 -> weight
// regs 96 (h2-packed), encoder MACs halved; decoder stays fp32 (96 regs,
// allocated after encoder weights die). Peak live ~125 regs -> fits 128.
// Precision: f16 noise reaches the output only through hT @ Wd (SCALE=0.05
// bottleneck); decoder->out path is fp32. Expected absmax ~1e-4 (thr 3.7e-4).
extern "C" __global__ __launch_bounds__(256)
void lstm_ae(const float* __restrict__ x,
             const float* __restrict__ We,
             const float* __restrict__ Ue,
             const float* __restrict__ be,
             const float* __restrict__ Wd,
             const float* __restrict__ Ud,
             const float* __restrict__ bd,
             const float* __restrict__ Wout,
             const float* __restrict__ bout,
             float* __restrict__ out)
{
    const int lane = threadIdx.x & 63;
    const int w    = threadIdx.x >> 6;
    const int b    = (blockIdx.x << 2) + w;
    const int j    = lane & 31;
    const bool lo  = lane < 32;
    const int colA = (lane & 31) | ((lane & 32) << 1);  // lo: j, hi: 64+j
    const int colB = colA + 32;                          // lo: 32+j, hi: 96+j

    __shared__ __align__(16) _Float16 xbufh[4][2][64];  // per-wave dbuf x row, f16
    __shared__ __align__(16) _Float16 hbufh[4][32];     // per-wave h, f16
    __shared__ float4 hbuf4[4][8];                      // per-wave h, fp32 (decoder)
    float* hbuff = (float*)&hbuf4[w][0];

    // ---- encoder weights: f16x2-packed, register-stationary (96 VGPRs) ----
    h2 weA2[32], weB2[32], uA2[16], uB2[16];
#pragma unroll
    for (int q = 0; q < 32; ++q) {
        weA2[q] = h2{(_Float16)We[(2 * q) * G_ + colA], (_Float16)We[(2 * q + 1) * G_ + colA]};
        weB2[q] = h2{(_Float16)We[(2 * q) * G_ + colB], (_Float16)We[(2 * q + 1) * G_ + colB]};
    }
#pragma unroll
    for (int q = 0; q < 16; ++q) {
        uA2[q] = h2{(_Float16)Ue[(2 * q) * G_ + colA], (_Float16)Ue[(2 * q + 1) * G_ + colA]};
        uB2[q] = h2{(_Float16)Ue[(2 * q) * G_ + colB], (_Float16)Ue[(2 * q + 1) * G_ + colB]};
    }
    const float beA = be[colA], beB = be[colB];

    const float* xrow = x + (size_t)b * (T_ * F_);

    // stage x[0] (f16); init h (f16)
    xbufh[w][0][lane] = (_Float16)xrow[lane];
    if (lo) hbufh[w][lane] = (_Float16)0.f;

    float c = 0.0f, hv = 0.0f;

    // =========================== encoder scan (f16 dot2) ===========================
#pragma unroll 1
    for (int t = 0; t < T_; ++t) {
        const int tn = (t + 1 < T_) ? (t + 1) : (T_ - 1);
        float xnext = xrow[tn * F_ + lane];

        float zA0 = 0.f, zA1 = 0.f, zB0 = 0.f, zB1 = 0.f;
        const float4* xb = (const float4*)&xbufh[w][t & 1][0];  // 8 x float4 = 64 f16
#pragma unroll
        for (int q = 0; q < 8; ++q) {
            float4 xq = xb[q];                 // broadcast ds_read_b128 (wave-uniform)
            const h2* xh = (const h2*)&xq;     // 4 h2 pairs
            int k = 4 * q;
            zA0 = dot2(xh[0], weA2[k + 0], zA0);
            zA1 = dot2(xh[1], weA2[k + 1], zA1);
            zA0 = dot2(xh[2], weA2[k + 2], zA0);
            zA1 = dot2(xh[3], weA2[k + 3], zA1);
            zB0 = dot2(xh[0], weB2[k + 0], zB0);
            zB1 = dot2(xh[1], weB2[k + 1], zB1);
            zB0 = dot2(xh[2], weB2[k + 2], zB0);
            zB1 = dot2(xh[3], weB2[k + 3], zB1);
        }
        const float4* hb = (const float4*)&hbufh[w][0];          // 4 x float4 = 32 f16
#pragma unroll
        for (int q = 0; q < 4; ++q) {
            float4 hq = hb[q];
            const h2* hh = (const h2*)&hq;
            int k = 4 * q;
            zA0 = dot2(hh[0], uA2[k + 0], zA0);
            zA1 = dot2(hh[1], uA2[k + 1], zA1);
            zA0 = dot2(hh[2], uA2[k + 2], zA0);
            zA1 = dot2(hh[3], uA2[k + 3], zA1);
            zB0 = dot2(hh[0], uB2[k + 0], zB0);
            zB1 = dot2(hh[1], uB2[k + 1], zB1);
            zB0 = dot2(hh[2], uB2[k + 2], zB0);
            zB1 = dot2(hh[3], uB2[k + 3], zB1);
        }
        float zA = beA + zA0 + zA1;
        float zB = beB + zB0 + zB1;

        // lo: zA=i(sig), zB=f(sig); hi: zA=g(relu), zB=o(sig)
        float sA = sigmoid_f(zA);
        float aA = lo ? sA : fmaxf(zA, 0.f);
        float aB = sigmoid_f(zB);
        float gg = __shfl_xor(aA, 32, 64);   // lo lanes receive g_j
        c = fmaf(aB, c, aA * gg);            // lo: c = f*c + i*g
        float r  = fmaxf(c, 0.f);
        float rr = __shfl_xor(r, 32, 64);    // hi lanes receive relu(c_j)
        hv = aB * rr;                        // hi: h_j = o * relu(c)
        if (!lo) hbufh[w][j] = (_Float16)hv;               // publish h_t (f16)
        xbufh[w][(t + 1) & 1][lane] = (_Float16)xnext;     // stage x_{t+1}
    }

    // publish hT in fp32 for the fp32 decoder path
    if (!lo) hbuff[j] = hv;

    // ============ decoder constant input: zd = hT@Wd + bd (fp32, once) ============
    float zdA = bd[colA], zdB = bd[colB];
#pragma unroll
    for (int q = 0; q < 8; ++q) {
        float4 hq = hbuf4[w][q];
        int k = 4 * q;
        zdA = fmaf(hq.x, Wd[(k + 0) * G_ + colA], zdA);
        zdA = fmaf(hq.y, Wd[(k + 1) * G_ + colA], zdA);
        zdA = fmaf(hq.z, Wd[(k + 2) * G_ + colA], zdA);
        zdA = fmaf(hq.w, Wd[(k + 3) * G_ + colA], zdA);
        zdB = fmaf(hq.x, Wd[(k + 0) * G_ + colB], zdB);
        zdB = fmaf(hq.y, Wd[(k + 1) * G_ + colB], zdB);
        zdB = fmaf(hq.z, Wd[(k + 2) * G_ + colB], zdB);
        zdB = fmaf(hq.w, Wd[(k + 3) * G_ + colB], zdB);
    }

    // decoder weights, fp32 (encoder h2 arrays dead -> RA reuses their registers)
    float udA[32], udB[32], wo[32];
#pragma unroll
    for (int k = 0; k < 32; ++k) {
        udA[k] = Ud[k * G_ + colA];
        udB[k] = Ud[k * G_ + colB];
        wo[k]  = Wout[k * F_ + lane];
    }
    const float bo = bout[lane];

    c = 0.f;
    if (lo) hbuff[lane] = 0.0f;   // h_{-1} = 0

    float* orow = out + (size_t)b * (T_ * F_);

    // ======= decoder scan (fp32); out-proj fused into h-read pass (1-step deferred) =======
#pragma unroll 1
    for (int t = 0; t < T_; ++t) {
        float hA0 = 0.f, hA1 = 0.f, hB0 = 0.f, hB1 = 0.f;
        float o0 = bo, o1 = 0.f;
#pragma unroll
        for (int q = 0; q < 8; ++q) {
            float4 hq = hbuf4[w][q];   // h_{t-1}
            int k = 4 * q;
            hA0 = fmaf(hq.x, udA[k + 0], hA0);
            hA1 = fmaf(hq.y, udA[k + 1], hA1);
            hA0 = fmaf(hq.z, udA[k + 2], hA0);
            hA1 = fmaf(hq.w, udA[k + 3], hA1);
            hB0 = fmaf(hq.x, udB[k + 0], hB0);
            hB1 = fmaf(hq.y, udB[k + 1], hB1);
            hB0 = fmaf(hq.z, udB[k + 2], hB0);
            hB1 = fmaf(hq.w, udB[k + 3], hB1);
            o0  = fmaf(hq.x, wo[k + 0], o0);
            o1  = fmaf(hq.y, wo[k + 1], o1);
            o0  = fmaf(hq.z, wo[k + 2], o0);
            o1  = fmaf(hq.w, wo[k + 3], o1);
        }
        if (t > 0) orow[(t - 1) * F_ + lane] = o0 + o1;  // out row for h_{t-1}

        float zA = zdA + hA0 + hA1;
        float zB = zdB + hB0 + hB1;

        float sA = sigmoid_f(zA);
        float aA = lo ? sA : fmaxf(zA, 0.f);
        float aB = sigmoid_f(zB);
        float gg = __shfl_xor(aA, 32, 64);
        c = fmaf(aB, c, aA * gg);
        float r  = fmaxf(c, 0.f);
        float rr = __shfl_xor(r, 32, 64);
        float hvd = aB * rr;
        if (!lo) hbuff[j] = hvd;             // publish h_t (fp32)
    }

    // epilogue: out row 127 from final h
    {
        float o0 = bo, o1 = 0.f;
#pragma unroll
        for (int q = 0; q < 8; ++q) {
            float4 hq = hbuf4[w][q];
            int k = 4 * q;
            o0 = fmaf(hq.x, wo[k + 0], o0);
            o1 = fmaf(hq.y, wo[k + 1], o1);
            o0 = fmaf(hq.z, wo[k + 2], o0);
            o1 = fmaf(hq.w, wo[k + 3], o1);
        }
        orow[(T_ - 1) * F_ + lane] = o0 + o1;
    }
}

extern "C" void kernel_launch(void* const* d_in, const int* in_sizes, int n_in,
                              void* d_out, int out_size, void* d_ws, size_t ws_size,
                              hipStream_t stream) {
    (void)in_sizes; (void)n_in; (void)d_ws; (void)ws_size; (void)out_size;
    const float* x    = (const float*)d_in[0];
    const float* We   = (const float*)d_in[1];
    const float* Ue   = (const float*)d_in[2];
    const float* be   = (const float*)d_in[3];
    const float* Wd   = (const float*)d_in[4];
    const float* Ud   = (const float*)d_in[5];
    const float* bd   = (const float*)d_in[6];
    const float* Wout = (const float*)d_in[7];
    const float* bout = (const float*)d_in[8];
    float* out = (float*)d_out;

    dim3 grid(B_ / 4), block(256);
    hipLaunchKernelGGL(lstm_ae, grid, block, 0, stream,
                       x, We, Ue, be, Wd, Ud, bd, Wout, bout, out);
}

// Round 5
// 610.909 us; speedup vs baseline: 1.4539x; 1.0013x over previous
//
#include <hip/hip_runtime.h>

typedef _Float16 h2 __attribute__((ext_vector_type(2)));

#define B_ 4096
#define T_ 128
#define F_ 64
#define H_ 32
#define G_ 128  // 4*H

__device__ __forceinline__ float sigmoid_f(float z) {
    return __builtin_amdgcn_rcpf(1.0f + __expf(-z));
}

// v_dot2_f32_f16: 2 f16 MACs, fp32 accumulate, full VALU rate.
__device__ __forceinline__ float dot2(h2 a, h2 b, float c) {
#if __has_builtin(__builtin_amdgcn_fdot2)
    return __builtin_amdgcn_fdot2(a, b, c, false);
#else
    return c + (float)a.x * (float)b.x + (float)a.y * (float)b.y;
#endif
}

// Scheduling fence: stops the pre-RA scheduler from hoisting the entire
// prologue's 192 weight loads above their converts (R1-R4: that inflates peak
// live registers to ~300, the allocator statically parks the overflow in AGPRs
// for the WHOLE kernel, occupancy drops to 1 wave/SIMD and every weight use
// pays an accvgpr copy). Fence every 4 iterations: 8-16 loads in flight.
#define SCHED_FENCE() __builtin_amdgcn_sched_barrier(0)

// One wave per batch element. Gate-pair layout:
//   lanes 0..31  (j=lane):    colA = j     (i_j),  colB = 32+j  (f_j)
//   lanes 32..63 (j=lane-32): colA = 64+j  (g_j),  colB = 96+j  (o_j)
// Encoder in f16-dot2 (weights h2-packed: 96 regs), decoder fp32 (96 regs,
// loaded after encoder weights die). Steady-state live ~135 regs.
extern "C" __global__ __launch_bounds__(256)
void lstm_ae(const float* __restrict__ x,
             const float* __restrict__ We,
             const float* __restrict__ Ue,
             const float* __restrict__ be,
             const float* __restrict__ Wd,
             const float* __restrict__ Ud,
             const float* __restrict__ bd,
             const float* __restrict__ Wout,
             const float* __restrict__ bout,
             float* __restrict__ out)
{
    const int lane = threadIdx.x & 63;
    const int w    = threadIdx.x >> 6;
    const int b    = (blockIdx.x << 2) + w;
    const int j    = lane & 31;
    const bool lo  = lane < 32;
    const int colA = (lane & 31) | ((lane & 32) << 1);  // lo: j, hi: 64+j
    const int colB = colA + 32;                          // lo: 32+j, hi: 96+j

    __shared__ __align__(16) _Float16 xbufh[4][2][64];  // per-wave dbuf x row, f16
    __shared__ __align__(16) _Float16 hbufh[4][32];     // per-wave h, f16
    __shared__ float4 hbuf4[4][8];                      // per-wave h, fp32 (decoder)
    float* hbuff = (float*)&hbuf4[w][0];

    // ---- encoder weights: f16x2-packed, register-stationary (96 VGPRs) ----
    h2 weA2[32], weB2[32], uA2[16], uB2[16];
#pragma unroll
    for (int q = 0; q < 32; ++q) {
        weA2[q] = h2{(_Float16)We[(2 * q) * G_ + colA], (_Float16)We[(2 * q + 1) * G_ + colA]};
        weB2[q] = h2{(_Float16)We[(2 * q) * G_ + colB], (_Float16)We[(2 * q + 1) * G_ + colB]};
        if ((q & 3) == 3) SCHED_FENCE();
    }
#pragma unroll
    for (int q = 0; q < 16; ++q) {
        uA2[q] = h2{(_Float16)Ue[(2 * q) * G_ + colA], (_Float16)Ue[(2 * q + 1) * G_ + colA]};
        uB2[q] = h2{(_Float16)Ue[(2 * q) * G_ + colB], (_Float16)Ue[(2 * q + 1) * G_ + colB]};
        if ((q & 3) == 3) SCHED_FENCE();
    }
    const float beA = be[colA], beB = be[colB];

    const float* xrow = x + (size_t)b * (T_ * F_);

    // stage x[0] (f16); init h (f16)
    xbufh[w][0][lane] = (_Float16)xrow[lane];
    if (lo) hbufh[w][lane] = (_Float16)0.f;

    float c = 0.0f, hv = 0.0f;

    // =========================== encoder scan (f16 dot2) ===========================
#pragma unroll 1
    for (int t = 0; t < T_; ++t) {
        const int tn = (t + 1 < T_) ? (t + 1) : (T_ - 1);
        float xnext = xrow[tn * F_ + lane];

        float zA0 = 0.f, zA1 = 0.f, zB0 = 0.f, zB1 = 0.f;
        const float4* xb = (const float4*)&xbufh[w][t & 1][0];  // 8 x float4 = 64 f16
#pragma unroll
        for (int q = 0; q < 8; ++q) {
            float4 xq = xb[q];                 // broadcast ds_read_b128 (wave-uniform)
            const h2* xh = (const h2*)&xq;     // 4 h2 pairs
            int k = 4 * q;
            zA0 = dot2(xh[0], weA2[k + 0], zA0);
            zA1 = dot2(xh[1], weA2[k + 1], zA1);
            zA0 = dot2(xh[2], weA2[k + 2], zA0);
            zA1 = dot2(xh[3], weA2[k + 3], zA1);
            zB0 = dot2(xh[0], weB2[k + 0], zB0);
            zB1 = dot2(xh[1], weB2[k + 1], zB1);
            zB0 = dot2(xh[2], weB2[k + 2], zB0);
            zB1 = dot2(xh[3], weB2[k + 3], zB1);
        }
        const float4* hb = (const float4*)&hbufh[w][0];          // 4 x float4 = 32 f16
#pragma unroll
        for (int q = 0; q < 4; ++q) {
            float4 hq = hb[q];
            const h2* hh = (const h2*)&hq;
            int k = 4 * q;
            zA0 = dot2(hh[0], uA2[k + 0], zA0);
            zA1 = dot2(hh[1], uA2[k + 1], zA1);
            zA0 = dot2(hh[2], uA2[k + 2], zA0);
            zA1 = dot2(hh[3], uA2[k + 3], zA1);
            zB0 = dot2(hh[0], uB2[k + 0], zB0);
            zB1 = dot2(hh[1], uB2[k + 1], zB1);
            zB0 = dot2(hh[2], uB2[k + 2], zB0);
            zB1 = dot2(hh[3], uB2[k + 3], zB1);
        }
        float zA = beA + zA0 + zA1;
        float zB = beB + zB0 + zB1;

        // lo: zA=i(sig), zB=f(sig); hi: zA=g(relu), zB=o(sig)
        float sA = sigmoid_f(zA);
        float aA = lo ? sA : fmaxf(zA, 0.f);
        float aB = sigmoid_f(zB);
        float gg = __shfl_xor(aA, 32, 64);   // lo lanes receive g_j
        c = fmaf(aB, c, aA * gg);            // lo: c = f*c + i*g
        float r  = fmaxf(c, 0.f);
        float rr = __shfl_xor(r, 32, 64);    // hi lanes receive relu(c_j)
        hv = aB * rr;                        // hi: h_j = o * relu(c)
        if (!lo) hbufh[w][j] = (_Float16)hv;               // publish h_t (f16)
        xbufh[w][(t + 1) & 1][lane] = (_Float16)xnext;     // stage x_{t+1}
    }

    // publish hT in fp32 for the fp32 decoder path
    if (!lo) hbuff[j] = hv;

    // ============ decoder constant input: zd = hT@Wd + bd (fp32, once) ============
    float zdA = bd[colA], zdB = bd[colB];
#pragma unroll
    for (int q = 0; q < 8; ++q) {
        float4 hq = hbuf4[w][q];
        int k = 4 * q;
        zdA = fmaf(hq.x, Wd[(k + 0) * G_ + colA], zdA);
        zdA = fmaf(hq.y, Wd[(k + 1) * G_ + colA], zdA);
        zdA = fmaf(hq.z, Wd[(k + 2) * G_ + colA], zdA);
        zdA = fmaf(hq.w, Wd[(k + 3) * G_ + colA], zdA);
        zdB = fmaf(hq.x, Wd[(k + 0) * G_ + colB], zdB);
        zdB = fmaf(hq.y, Wd[(k + 1) * G_ + colB], zdB);
        zdB = fmaf(hq.z, Wd[(k + 2) * G_ + colB], zdB);
        zdB = fmaf(hq.w, Wd[(k + 3) * G_ + colB], zdB);
        if ((q & 1) == 1) SCHED_FENCE();
    }

    // decoder weights, fp32 (encoder h2 arrays dead -> RA reuses their registers)
    float udA[32], udB[32], wo[32];
#pragma unroll
    for (int k = 0; k < 32; ++k) {
        udA[k] = Ud[k * G_ + colA];
        udB[k] = Ud[k * G_ + colB];
        wo[k]  = Wout[k * F_ + lane];
        if ((k & 3) == 3) SCHED_FENCE();
    }
    const float bo = bout[lane];

    c = 0.f;
    if (lo) hbuff[lane] = 0.0f;   // h_{-1} = 0

    float* orow = out + (size_t)b * (T_ * F_);

    // ======= decoder scan (fp32); out-proj fused into h-read pass (1-step deferred) =======
#pragma unroll 1
    for (int t = 0; t < T_; ++t) {
        float hA0 = 0.f, hA1 = 0.f, hB0 = 0.f, hB1 = 0.f;
        float o0 = bo, o1 = 0.f;
#pragma unroll
        for (int q = 0; q < 8; ++q) {
            float4 hq = hbuf4[w][q];   // h_{t-1}
            int k = 4 * q;
            hA0 = fmaf(hq.x, udA[k + 0], hA0);
            hA1 = fmaf(hq.y, udA[k + 1], hA1);
            hA0 = fmaf(hq.z, udA[k + 2], hA0);
            hA1 = fmaf(hq.w, udA[k + 3], hA1);
            hB0 = fmaf(hq.x, udB[k + 0], hB0);
            hB1 = fmaf(hq.y, udB[k + 1], hB1);
            hB0 = fmaf(hq.z, udB[k + 2], hB0);
            hB1 = fmaf(hq.w, udB[k + 3], hB1);
            o0  = fmaf(hq.x, wo[k + 0], o0);
            o1  = fmaf(hq.y, wo[k + 1], o1);
            o0  = fmaf(hq.z, wo[k + 2], o0);
            o1  = fmaf(hq.w, wo[k + 3], o1);
        }
        if (t > 0) orow[(t - 1) * F_ + lane] = o0 + o1;  // out row for h_{t-1}

        float zA = zdA + hA0 + hA1;
        float zB = zdB + hB0 + hB1;

        float sA = sigmoid_f(zA);
        float aA = lo ? sA : fmaxf(zA, 0.f);
        float aB = sigmoid_f(zB);
        float gg = __shfl_xor(aA, 32, 64);
        c = fmaf(aB, c, aA * gg);
        float r  = fmaxf(c, 0.f);
        float rr = __shfl_xor(r, 32, 64);
        float hvd = aB * rr;
        if (!lo) hbuff[j] = hvd;             // publish h_t (fp32)
    }

    // epilogue: out row 127 from final h
    {
        float o0 = bo, o1 = 0.f;
#pragma unroll
        for (int q = 0; q < 8; ++q) {
            float4 hq = hbuf4[w][q];
            int k = 4 * q;
            o0 = fmaf(hq.x, wo[k + 0], o0);
            o1 = fmaf(hq.y, wo[k + 1], o1);
            o0 = fmaf(hq.z, wo[k + 2], o0);
            o1 = fmaf(hq.w, wo[k + 3], o1);
        }
        orow[(T_ - 1) * F_ + lane] = o0 + o1;
    }
}

extern "C" void kernel_launch(void* const* d_in, const int* in_sizes, int n_in,
                              void* d_out, int out_size, void* d_ws, size_t ws_size,
                              hipStream_t stream) {
    (void)in_sizes; (void)n_in; (void)d_ws; (void)ws_size; (void)out_size;
    const float* x    = (const float*)d_in[0];
    const float* We   = (const float*)d_in[1];
    const float* Ue   = (const float*)d_in[2];
    const float* be   = (const float*)d_in[3];
    const float* Wd   = (const float*)d_in[4];
    const float* Ud   = (const float*)d_in[5];
    const float* bd   = (const float*)d_in[6];
    const float* Wout = (const float*)d_in[7];
    const float* bout = (const float*)d_in[8];
    float* out = (float*)d_out;

    dim3 grid(B_ / 4), block(256);
    hipLaunchKernelGGL(lstm_ae, grid, block, 0, stream,
                       x, We, Ue, be, Wd, Ud, bd, Wout, bout, out);
}